// Round 1
// baseline (14637.553 us; speedup 1.0000x reference)
//
#include <hip/hip_runtime.h>
#include <cstdint>
#include <cstddef>

// ---------------------------------------------------------------------------
// GumbelRNNGenerator: B=128, NOISE=128, H=512, V=5000, T=128 sequential steps.
// Everything fp32 (argmax-exactness). JAX threefry partitionable PRNG.
// PARTITIONABLE=1: modern JAX (>=0.4.30) default. If bench absmax ~1.0 with
// everything else sane, flip to 0 (legacy iota-halves random_bits + split).
// ---------------------------------------------------------------------------
#define PARTITIONABLE 1

#define B_SZ 128
#define NOISE_SZ 128
#define H 512
#define H2 1024
#define H3 1536
#define V_SZ 5000
#define BN_EPS 1e-5f

// ------------------------------- Threefry ---------------------------------
__device__ __forceinline__ uint32_t rotl32(uint32_t v, int r) {
  return (v << r) | (v >> (32 - r));
}

__device__ __forceinline__ void threefry2x32(uint32_t k0, uint32_t k1,
                                             uint32_t x0, uint32_t x1,
                                             uint32_t& o0, uint32_t& o1) {
  uint32_t k2 = k0 ^ k1 ^ 0x1BD11BDAu;
  x0 += k0; x1 += k1;
#define TFR(r) { x0 += x1; x1 = rotl32(x1, (r)); x1 ^= x0; }
  TFR(13) TFR(15) TFR(26) TFR(6)
  x0 += k1; x1 += k2 + 1u;
  TFR(17) TFR(29) TFR(16) TFR(24)
  x0 += k2; x1 += k0 + 2u;
  TFR(13) TFR(15) TFR(26) TFR(6)
  x0 += k0; x1 += k1 + 3u;
  TFR(17) TFR(29) TFR(16) TFR(24)
  x0 += k1; x1 += k2 + 4u;
  TFR(13) TFR(15) TFR(26) TFR(6)
  x0 += k2; x1 += k0 + 5u;
#undef TFR
  o0 = x0; o1 = x1;
}

__device__ __forceinline__ float lrelu_(float x) { return x >= 0.f ? x : 0.2f * x; }

__device__ __forceinline__ float sigmoidf_(float x) {
  // stable logistic, matches jax.nn.sigmoid to ~1 ulp
  return (x >= 0.f) ? 1.f / (1.f + expf(-x)) : expf(x) / (1.f + expf(x));
}

// ------------------------ init: subkey chain + prev ------------------------
__global__ void k_init(uint32_t* __restrict__ subkeys, int* __restrict__ prev, int T) {
  const int tid = threadIdx.x;
  if (tid < B_SZ) prev[tid] = V_SZ - 1;  // SOS
  if (tid == 0) {
    uint32_t k0 = 0u, k1 = 42u;  // jax.random.key(42) -> [0, 42]
    for (int t = 0; t < T; ++t) {
      uint32_t a0, a1, b0, b1;
#if PARTITIONABLE
      // foldlike split: counts hi=[0,0], lo=[0,1]
      threefry2x32(k0, k1, 0u, 0u, a0, a1);  // new key
      threefry2x32(k0, k1, 0u, 1u, b0, b1);  // subkey
      subkeys[2 * t] = b0; subkeys[2 * t + 1] = b1;
      k0 = a0; k1 = a1;
#else
      // original split: counts iota(4) -> blocks (0,2),(1,3)
      uint32_t c0h, c0l, c1h, c1l;
      threefry2x32(k0, k1, 0u, 2u, c0h, c0l);
      threefry2x32(k0, k1, 1u, 3u, c1h, c1l);
      subkeys[2 * t] = c0l; subkeys[2 * t + 1] = c1l;  // sub = out1 pair
      k0 = c0h; k1 = c1h;                               // key = out0 pair
#endif
    }
  }
}

// ------------------- setup: a = lrelu(z @ W_z2h^T + b) ---------------------
__global__ __launch_bounds__(128) void k_z2h(const float* __restrict__ z,
                                             const float* __restrict__ W,
                                             const float* __restrict__ bias,
                                             float* __restrict__ a) {
  const int j = blockIdx.x;   // 0..H-1
  const int b = threadIdx.x;  // 0..B-1
  const float* zr = z + (size_t)b * NOISE_SZ;
  const float* wr = W + (size_t)j * NOISE_SZ;
  float acc = 0.f;
#pragma unroll 8
  for (int k = 0; k < NOISE_SZ; ++k) acc = fmaf(zr[k], wr[k], acc);
  a[(size_t)b * H + j] = lrelu_(acc + bias[j]);
}

// ------------- generic per-column batchnorm over batch (grid=H) ------------
__global__ __launch_bounds__(128) void k_bncol(const float* __restrict__ in,
                                               const float* __restrict__ g,
                                               const float* __restrict__ be,
                                               float* __restrict__ out,
                                               float* __restrict__ out2) {
  const int j = blockIdx.x, b = threadIdx.x;
  __shared__ float red[128];
  const float x = in[(size_t)b * H + j];
  red[b] = x; __syncthreads();
#pragma unroll
  for (int s = 64; s > 0; s >>= 1) { if (b < s) red[b] += red[b + s]; __syncthreads(); }
  const float m = red[0] * (1.f / 128.f);
  __syncthreads();
  const float d = x - m;
  red[b] = d * d; __syncthreads();
#pragma unroll
  for (int s = 64; s > 0; s >>= 1) { if (b < s) red[b] += red[b + s]; __syncthreads(); }
  const float v = red[0] * (1.f / 128.f);
  const float y = g[j] * (x - m) / sqrtf(v + BN_EPS) + be[j];
  out[(size_t)b * H + j] = y;
  if (out2) out2[(size_t)b * H + j] = y;
}

// ------------- per step: si_x = bn(lrelu(emb[prev]))[cols 0..H) ------------
__global__ __launch_bounds__(128) void k_embed_bn(const float* __restrict__ emb,
                                                  const int* __restrict__ prev,
                                                  const float* __restrict__ g2,
                                                  const float* __restrict__ be2,
                                                  float* __restrict__ si_x) {
  const int j = blockIdx.x, b = threadIdx.x;
  __shared__ float red[128];
  const float x = lrelu_(emb[(size_t)prev[b] * H + j]);
  red[b] = x; __syncthreads();
#pragma unroll
  for (int s = 64; s > 0; s >>= 1) { if (b < s) red[b] += red[b + s]; __syncthreads(); }
  const float m = red[0] * (1.f / 128.f);
  __syncthreads();
  const float d = x - m;
  red[b] = d * d; __syncthreads();
#pragma unroll
  for (int s = 64; s > 0; s >>= 1) { if (b < s) red[b] += red[b + s]; __syncthreads(); }
  const float v = red[0] * (1.f / 128.f);
  si_x[(size_t)b * H + j] = g2[j] * (x - m) / sqrtf(v + BN_EPS) + be2[j];
}

// --------------- per step: GRU gates + o = bn(lrelu(h_new)) ----------------
__global__ __launch_bounds__(128) void k_gru_bn(const float* __restrict__ gi,
                                                const float* __restrict__ gh,
                                                float* __restrict__ h,
                                                const float* __restrict__ g3,
                                                const float* __restrict__ be3,
                                                float* __restrict__ o) {
  const int j = blockIdx.x, b = threadIdx.x;
  __shared__ float red[128];
  const float* gib = gi + (size_t)b * H3;
  const float* ghb = gh + (size_t)b * H3;
  const float r  = sigmoidf_(gib[j] + ghb[j]);
  const float zt = sigmoidf_(gib[H + j] + ghb[H + j]);
  const float n  = tanhf(gib[2 * H + j] + r * ghb[2 * H + j]);
  const float hold = h[(size_t)b * H + j];
  const float hnew = (1.f - zt) * n + zt * hold;
  h[(size_t)b * H + j] = hnew;
  const float x = lrelu_(hnew);
  red[b] = x; __syncthreads();
#pragma unroll
  for (int s = 64; s > 0; s >>= 1) { if (b < s) red[b] += red[b + s]; __syncthreads(); }
  const float m = red[0] * (1.f / 128.f);
  __syncthreads();
  const float d = x - m;
  red[b] = d * d; __syncthreads();
#pragma unroll
  for (int s = 64; s > 0; s >>= 1) { if (b < s) red[b] += red[b + s]; __syncthreads(); }
  const float v = red[0] * (1.f / 128.f);
  o[(size_t)b * H + j] = g3[j] * (x - m) / sqrtf(v + BN_EPS) + be3[j];
}

// ------------------------------ GEMM C = A·Wᵀ ------------------------------
// A: [128, K] row-major (lda=K). W: [N, K] row-major (ldw). Epilogue adds
// bias[n] or full[m][n]. Dual-problem launch via blockIdx.z.
struct GemmP {
  const float* A;
  const float* W;
  const float* bias;   // [N] or nullptr
  const float* full;   // [128, fullld] or nullptr
  float* C;
  long long ldc;
  int N, K, lda, ldw, fullld;
};

#define BM 64
#define BN 32
#define BK 32

__global__ __launch_bounds__(256) void gemm_dual(GemmP P0, GemmP P1) {
  GemmP p = (blockIdx.z == 0) ? P0 : P1;
  const int n0 = blockIdx.x * BN;
  const int m0 = blockIdx.y * BM;
  __shared__ float As[BK][BM + 4];  // transposed: As[k][m], row stride 272B (16B-aligned)
  __shared__ float Ws[BK][BN + 4];  // transposed: Ws[k][n]
  const int tid = threadIdx.x;
  const int tx = tid & 15;   // -> 2 cols
  const int ty = tid >> 4;   // -> 4 rows
  const int c  = tid & 31;   // k within tile (coalesced global reads)
  const int r0 = tid >> 5;
  float acc[4][2] = {{0.f, 0.f}, {0.f, 0.f}, {0.f, 0.f}, {0.f, 0.f}};
  for (int k0 = 0; k0 < p.K; k0 += BK) {
#pragma unroll
    for (int i = 0; i < 8; ++i) {
      const int r = r0 + i * 8;
      As[c][r] = p.A[(size_t)(m0 + r) * p.lda + k0 + c];
    }
#pragma unroll
    for (int i = 0; i < 4; ++i) {
      const int n = r0 + i * 8;
      Ws[c][n] = (n0 + n < p.N) ? p.W[(size_t)(n0 + n) * p.ldw + k0 + c] : 0.f;
    }
    __syncthreads();
#pragma unroll
    for (int kk = 0; kk < BK; ++kk) {
      const float4 av = *(const float4*)&As[kk][ty * 4];
      const float2 wv = *(const float2*)&Ws[kk][tx * 2];
      acc[0][0] += av.x * wv.x; acc[0][1] += av.x * wv.y;
      acc[1][0] += av.y * wv.x; acc[1][1] += av.y * wv.y;
      acc[2][0] += av.z * wv.x; acc[2][1] += av.z * wv.y;
      acc[3][0] += av.w * wv.x; acc[3][1] += av.w * wv.y;
    }
    __syncthreads();
  }
#pragma unroll
  for (int i = 0; i < 4; ++i) {
    const int m = m0 + ty * 4 + i;
#pragma unroll
    for (int j = 0; j < 2; ++j) {
      const int n = n0 + tx * 2 + j;
      if (n < p.N) {
        const float add = p.full ? p.full[(size_t)m * p.fullld + n] : p.bias[n];
        p.C[(long long)m * p.ldc + n] = acc[i][j] + add;
      }
    }
  }
}

// ----------- per step: gumbel noise + softmax + argmax (block = b) ---------
__global__ __launch_bounds__(256) void k_gumbel(float* __restrict__ out,
                                                const float* __restrict__ temp_ptr,
                                                const uint32_t* __restrict__ subkeys,
                                                int* __restrict__ prev,
                                                int t, int T) {
  const int b = blockIdx.x;
  const int tid = threadIdx.x;
  float* row = out + ((size_t)b * T + t) * V_SZ;  // logits pre-written here
  __shared__ float sy[V_SZ];
  __shared__ float red[256];
  __shared__ int redi[256];
  const uint32_t k0 = subkeys[2 * t], k1 = subkeys[2 * t + 1];
  const float temp = *temp_ptr;

  // pass 1: y = (logit + gumbel) / temp
  float lmax = -3.4e38f;
  for (int j = tid; j < V_SZ; j += 256) {
    uint32_t bits;
#if PARTITIONABLE
    uint32_t o0, o1;
    threefry2x32(k0, k1, 0u, (uint32_t)(b * V_SZ + j), o0, o1);
    bits = o0 ^ o1;
#else
    const uint32_t half = (uint32_t)(B_SZ * V_SZ / 2);
    const uint32_t i = (uint32_t)(b * V_SZ + j);
    uint32_t o0, o1;
    if (i < half) { threefry2x32(k0, k1, i, i + half, o0, o1); bits = o0; }
    else          { threefry2x32(k0, k1, i - half, i, o0, o1); bits = o1; }
#endif
    // jax._uniform: bitcast((bits>>9)|0x3f800000)-1 ; *(1-1e-20)+1e-20 ; max(1e-20,·)
    const float f = __uint_as_float((bits >> 9) | 0x3f800000u) - 1.0f;
    const float u = fmaxf(1e-20f, f + 1e-20f);
    const float gum = -logf(-logf(u));
    const float y = (row[j] + gum) / temp;
    sy[j] = y;
    lmax = fmaxf(lmax, y);
  }
  red[tid] = lmax; __syncthreads();
#pragma unroll
  for (int s = 128; s > 0; s >>= 1) { if (tid < s) red[tid] = fmaxf(red[tid], red[tid + s]); __syncthreads(); }
  const float m = red[0];
  __syncthreads();

  // pass 2: exp + sum
  float lsum = 0.f;
  for (int j = tid; j < V_SZ; j += 256) { const float e = expf(sy[j] - m); sy[j] = e; lsum += e; }
  red[tid] = lsum; __syncthreads();
#pragma unroll
  for (int s = 128; s > 0; s >>= 1) { if (tid < s) red[tid] += red[tid + s]; __syncthreads(); }
  const float S = red[0];
  __syncthreads();

  // pass 3: p = e/S, write, argmax (first-occurrence tiebreak)
  float bmax = -1.f; int bidx = 0x7fffffff;
  for (int j = tid; j < V_SZ; j += 256) {
    const float p = sy[j] / S;
    row[j] = p;
    if (p > bmax) { bmax = p; bidx = j; }
  }
  red[tid] = bmax; redi[tid] = bidx; __syncthreads();
#pragma unroll
  for (int s = 128; s > 0; s >>= 1) {
    if (tid < s) {
      const float v2 = red[tid + s]; const int i2 = redi[tid + s];
      if (v2 > red[tid] || (v2 == red[tid] && i2 < redi[tid])) { red[tid] = v2; redi[tid] = i2; }
    }
    __syncthreads();
  }
  if (tid == 0) prev[b] = redi[0];
}

// ---------------------------------------------------------------------------
extern "C" void kernel_launch(void* const* d_in, const int* in_sizes, int n_in,
                              void* d_out, int out_size, void* d_ws, size_t ws_size,
                              hipStream_t stream) {
  const float* z     = (const float*)d_in[0];
  const float* temp  = (const float*)d_in[1];
  // d_in[2] = num_steps (device int) — T derived from out_size instead
  const float* W_z2h = (const float*)d_in[3];
  const float* b_z2h = (const float*)d_in[4];
  const float* g1    = (const float*)d_in[5];
  const float* be1   = (const float*)d_in[6];
  const float* emb   = (const float*)d_in[7];
  const float* g2    = (const float*)d_in[8];
  const float* be2   = (const float*)d_in[9];
  const float* W_ih  = (const float*)d_in[10];
  const float* b_ih  = (const float*)d_in[11];
  const float* W_hh  = (const float*)d_in[12];
  const float* b_hh  = (const float*)d_in[13];
  const float* g3    = (const float*)d_in[14];
  const float* be3   = (const float*)d_in[15];
  const float* W_h2o = (const float*)d_in[16];
  const float* b_h2o = (const float*)d_in[17];
  float* out = (float*)d_out;
  const int T = out_size / (B_SZ * V_SZ);  // 128

  // workspace layout (floats)
  float* fws  = (float*)d_ws;
  float* si_x = fws;                 // 128*512
  float* si_z = fws + 65536;         // 128*512
  float* h    = fws + 131072;        // 128*512
  float* o    = fws + 196608;        // 128*512
  float* gi   = fws + 262144;        // 128*1536
  float* gh   = fws + 458752;        // 128*1536
  float* gi_z = fws + 655360;        // 128*1536
  float* zbn  = fws + 851968;        // 128*512
  uint32_t* subkeys = (uint32_t*)(fws + 917504);  // 2*T (room for 256)
  int* prev = (int*)(subkeys + 512);              // B

  // ---- setup (once per launch; deterministic) ----
  k_init<<<1, 128, 0, stream>>>(subkeys, prev, T);
  k_z2h<<<H, B_SZ, 0, stream>>>(z, W_z2h, b_z2h, si_x);           // si_x used as scratch 'a'
  k_bncol<<<H, B_SZ, 0, stream>>>(si_x, g1, be1, zbn, h);         // zbn + h0
  k_bncol<<<H, B_SZ, 0, stream>>>(zbn, g2 + H, be2 + H, si_z, nullptr);

  // gi_z = si_z @ W_ih[:, H:2H]^T + b_ih   (step-invariant half of gi)
  GemmP pz; pz.A = si_z; pz.W = W_ih + H; pz.bias = b_ih; pz.full = nullptr;
  pz.C = gi_z; pz.ldc = H3; pz.N = H3; pz.K = H; pz.lda = H; pz.ldw = H2; pz.fullld = 0;
  gemm_dual<<<dim3(H3 / BN, 2, 1), 256, 0, stream>>>(pz, pz);

  // ---- per-step problem descriptors ----
  GemmP pgi; pgi.A = si_x; pgi.W = W_ih; pgi.bias = nullptr; pgi.full = gi_z;
  pgi.C = gi; pgi.ldc = H3; pgi.N = H3; pgi.K = H; pgi.lda = H; pgi.ldw = H2; pgi.fullld = H3;
  GemmP pgh; pgh.A = h; pgh.W = W_hh; pgh.bias = b_hh; pgh.full = nullptr;
  pgh.C = gh; pgh.ldc = H3; pgh.N = H3; pgh.K = H; pgh.lda = H; pgh.ldw = H; pgh.fullld = 0;
  GemmP plg; plg.A = o; plg.W = W_h2o; plg.bias = b_h2o; plg.full = nullptr;
  plg.ldc = (long long)T * V_SZ; plg.N = V_SZ; plg.K = H; plg.lda = H; plg.ldw = H; plg.fullld = 0;

  for (int t = 0; t < T; ++t) {
    k_embed_bn<<<H, B_SZ, 0, stream>>>(emb, prev, g2, be2, si_x);
    gemm_dual<<<dim3(H3 / BN, 2, 2), 256, 0, stream>>>(pgi, pgh);
    k_gru_bn<<<H, B_SZ, 0, stream>>>(gi, gh, h, g3, be3, o);
    plg.C = out + (size_t)t * V_SZ;  // logits straight into d_out row (b, t, :)
    gemm_dual<<<dim3((V_SZ + BN - 1) / BN, 2, 1), 256, 0, stream>>>(plg, plg);
    k_gumbel<<<B_SZ, 256, 0, stream>>>(out, temp, subkeys, prev, t, T);
  }
}